// Round 7
// baseline (534.519 us; speedup 1.0000x reference)
//
#include <hip/hip_runtime.h>
#include <hip/hip_bf16.h>
#include <math.h>

#define CIN   2048
#define CMID  1024
#define NB    32
#define HWSP  196
#define NPOS  6272      // 32*196
#define WELEM 2097152   // CMID*CIN
#define NSTEP 288       // K-steps per z-chunk (BK=32, total K=18432 split in 2)

typedef __attribute__((ext_vector_type(4))) float f32x4;
typedef __attribute__((ext_vector_type(8))) short short8;

typedef const __attribute__((address_space(1))) unsigned int* as1_u32p;
typedef __attribute__((address_space(3))) unsigned int* as3_u32p;

__device__ __forceinline__ void gload_lds16(const void* g, void* l) {
  __builtin_amdgcn_global_load_lds((as1_u32p)g, (as3_u32p)l, 16, 0, 0);
}

// ---------------- pack weights: w1 -> Wpf[g=576][m=1024][k=32] bf16 (fragment-major),
// BN fold, head-weight transpose
__global__ __launch_bounds__(256) void pack_w(
    const float* __restrict__ w1, const float* __restrict__ b1,
    const float* __restrict__ g1, const float* __restrict__ be1,
    const float* __restrict__ mu1, const float* __restrict__ va1,
    const float* __restrict__ wsel, const float* __restrict__ wbox,
    __hip_bfloat16* __restrict__ Wp, float* __restrict__ inv1,
    float* __restrict__ add1, float* __restrict__ Wh)
{
  const int gid = blockIdx.x * 256 + threadIdx.x;
  if (gid < WELEM) {
    const int m = gid >> 11, c = gid & 2047;
    const int kc = c >> 5, kl = c & 31;
    const float* src = w1 + (long)gid * 9;
    float v[9];
    #pragma unroll
    for (int k = 0; k < 9; ++k) v[k] = src[k];
    #pragma unroll
    for (int k = 0; k < 9; ++k)
      Wp[(((long)(k * 64 + kc) * 1024 + m) << 5) + kl] = __float2bfloat16(v[k]);
  }
  if (gid < CMID) {
    float iv = g1[gid] / sqrtf(va1[gid] + 1e-5f);
    inv1[gid] = iv;
    add1[gid] = b1[gid] * iv + be1[gid] - mu1[gid] * iv;
  }
  if (gid < CMID * 54) {
    int co = gid / 54, o = gid % 54;
    Wh[gid] = (o < 18) ? wsel[o * CMID + co] : wbox[(o - 18) * CMID + co];
  }
}

// ---------------- pack x: NCHW fp32 -> Xpad[32][16][16][2048] bf16 (zero border)
__global__ __launch_bounds__(256) void pack_x(
    const float* __restrict__ x, __hip_bfloat16* __restrict__ Xp)
{
  __shared__ __hip_bfloat16 lx[64 * HWSP];
  const int n = blockIdx.x;      // 0..31
  const int cc = blockIdx.y;     // 0..31
  const int ci0 = cc * 64;
  const float* src = x + ((long)n * CIN + ci0) * HWSP;
  for (int i = threadIdx.x; i < 64 * HWSP; i += 256)
    lx[i] = __float2bfloat16(src[i]);
  __syncthreads();
  const int ci = threadIdx.x & 63;
  const int pq = threadIdx.x >> 6;   // 0..3
  __hip_bfloat16* dst = Xp + (long)n * 256 * CIN + ci0 + ci;
  const __hip_bfloat16 z = __float2bfloat16(0.f);
  #pragma unroll
  for (int k = 0; k < 64; ++k) {
    int pos = k * 4 + pq;
    int y = pos >> 4, xx = pos & 15;
    __hip_bfloat16 v = z;
    if (y >= 1 && y <= 14 && xx >= 1 && xx <= 14)
      v = lx[ci * HWSP + (y - 1) * 14 + (xx - 1)];
    dst[(long)pos * CIN] = v;
  }
}

// ---------------- conv 3x3 as shifted GEMMs, split-K halves (288 BK32-steps each)
// 128x128 tile, 4 waves x (64x64), 16x16x32 bf16 MFMA.
// A: DIRECT global->VGPR (fragment-major Wpf, coalesced 1KB/load, L2-resident per XCD
//    since bid%8 == mtile). B: swizzled LDS ring-3 (24KB). Counted vmcnt(2)/half-step.
__global__ __launch_bounds__(256, 3) void conv_mfma(
    const short8* __restrict__ Apf8,
    const __hip_bfloat16* __restrict__ Xp,
    __hip_bfloat16* __restrict__ hout0,
    __hip_bfloat16* __restrict__ hout1)
{
  __shared__ char smem[3 * 8192];   // B ring of 3

  const int t = threadIdx.x;
  const int mtile = blockIdx.x;   // 0..7
  const int ntile = blockIdx.y;   // 0..48
  const int z = blockIdx.z;       // 0..1
  const int lane = t & 63;
  const int wv = t >> 6;          // 0..3
  const int wr2 = wv >> 1;        // 0..1 -> M offset *64
  const int wc2 = wv & 1;         // 0..1 -> N offset *64

  // B staging: thread t covers row (t>>2)+64*i, 16B chunk (t&3), XOR-preswizzled source
  const int srow = t >> 2;                                   // 0..63
  const int swb = ((t & 3) << 4) ^ ((srow & 6) << 3);        // byte offset in 64B row

  long bbase[2];
  #pragma unroll
  for (int i = 0; i < 2; ++i) {
    int jj = ntile * 128 + srow + 64 * i;
    int n0 = jj / HWSP, p0 = jj % HWSP;
    int hh = p0 / 14, ww = p0 % 14;
    bbase[i] = (long)(n0 * 256 + hh * 16 + ww) * CIN + (swb >> 1);
  }

  const int fr = lane & 15;
  const int ksl = lane >> 4;                                 // 0..3 K-slice
  const int kgsw = ((ksl << 4) ^ ((fr & 6) << 3));           // B frag-read swizzle const
  const long arowf = (long)(mtile * 128 + wr2 * 64 + fr);    // A frag row base

  f32x4 acc[4][4] = {};
  short8 aA[4], aB[4];

  const int g0 = z * NSTEP;

  #define LOAD_A(dst, gv) do {                                                  \
    long ab_ = ((((long)(gv) << 10) + arowf) << 2) + ksl;                       \
    _Pragma("unroll")                                                           \
    for (int i_ = 0; i_ < 4; ++i_) dst[i_] = Apf8[ab_ + (i_ << 6)];             \
  } while (0)

  #define STAGE_B(gv, bi) do {                                                  \
    int g_ = (gv);                                                              \
    int kt_ = g_ >> 6;                                                          \
    int ck_ = (g_ & 63) << 5;                                                   \
    int kh_ = (kt_ * 11) >> 5;                                                  \
    int kw_ = kt_ - kh_ * 3;                                                    \
    char* d_ = smem + (bi) * 8192;                                              \
    long boff_ = (long)(kh_ * 16 + kw_) * CIN + ck_;                            \
    _Pragma("unroll")                                                           \
    for (int i_ = 0; i_ < 2; ++i_)                                              \
      gload_lds16(Xp + bbase[i_] + boff_, d_ + i_ * 4096 + t * 16);             \
  } while (0)

  #define COMPUTE(av, bi) do {                                                  \
    const char* cb_ = smem + (bi) * 8192;                                       \
    short8 b_[4];                                                               \
    _Pragma("unroll")                                                           \
    for (int i = 0; i < 4; ++i)                                                 \
      b_[i] = *(const short8*)(cb_ + (wc2 * 64 + i * 16 + fr) * 64 + kgsw);     \
    _Pragma("unroll")                                                           \
    for (int m = 0; m < 4; ++m)                                                 \
      _Pragma("unroll")                                                         \
      for (int n = 0; n < 4; ++n)                                               \
        acc[m][n] = __builtin_amdgcn_mfma_f32_16x16x32_bf16(av[m], b_[n], acc[m][n], 0, 0, 0); \
  } while (0)

  #define WAITV2() asm volatile("s_waitcnt vmcnt(2)" ::: "memory")
  #define WAITV0() asm volatile("s_waitcnt vmcnt(0)" ::: "memory")
  #define BAR() do { asm volatile("" ::: "memory");                             \
                     __builtin_amdgcn_s_barrier();                              \
                     asm volatile("" ::: "memory"); } while (0)

  // prologue: A(0) to regs; B(0), B(1) to LDS ring
  LOAD_A(aA, g0 + 0);
  STAGE_B(g0 + 0, 0);
  STAGE_B(g0 + 1, 1);

  int bc = 0;                       // compute-buffer for step s
  for (int s = 0; s < NSTEP - 2; s += 2) {
    // half-step s (even): compute aA, prefetch aB
    WAITV2(); BAR();
    LOAD_A(aB, g0 + s + 1);
    { int bs_ = bc + 2; if (bs_ >= 3) bs_ -= 3; STAGE_B(g0 + s + 2, bs_); }
    COMPUTE(aA, bc);
    if (++bc == 3) bc = 0;
    // half-step s+1 (odd): compute aB, prefetch aA
    WAITV2(); BAR();
    LOAD_A(aA, g0 + s + 2);
    { int bs_ = bc + 2; if (bs_ >= 3) bs_ -= 3; STAGE_B(g0 + s + 3, bs_); }
    COMPUTE(aB, bc);
    if (++bc == 3) bc = 0;
  }
  // tail: steps NSTEP-2 (aA) and NSTEP-1 (aB)
  WAITV2(); BAR();
  LOAD_A(aB, g0 + NSTEP - 1);
  COMPUTE(aA, bc);
  if (++bc == 3) bc = 0;
  WAITV0(); BAR();
  COMPUTE(aB, bc);

  // epilogue: bf16 raw conv partials (BN/ReLU fused in head)
  __hip_bfloat16* dsth = z ? hout1 : hout0;
  const int rg = ksl * 4;
  #pragma unroll
  for (int m = 0; m < 4; ++m) {
    const int co0 = mtile * 128 + wr2 * 64 + m * 16 + rg;
    #pragma unroll
    for (int r = 0; r < 4; ++r) {
      const int co = co0 + r;
      #pragma unroll
      for (int n = 0; n < 4; ++n) {
        const int j = ntile * 128 + wc2 * 64 + n * 16 + fr;
        dsth[(long)co * NPOS + j] = __float2bfloat16(acc[m][n][r]);
      }
    }
  }
  #undef LOAD_A
  #undef STAGE_B
  #undef COMPUTE
  #undef WAITV2
  #undef WAITV0
  #undef BAR
}

// ---------------- fused 1x1 heads: sum partials + BN1/ReLU + heads + softmax/BN/reshape
__global__ __launch_bounds__(256) void head_fused(
    const __hip_bfloat16* __restrict__ h0, const __hip_bfloat16* __restrict__ h1,
    const float* __restrict__ Wh,
    const float* __restrict__ inv1, const float* __restrict__ add1,
    const float* __restrict__ bsel, const float* __restrict__ bbox,
    const float* __restrict__ gb, const float* __restrict__ beb,
    const float* __restrict__ mub, const float* __restrict__ vab,
    float* __restrict__ out)
{
  __shared__ float red[4 * 64 * 54];
  const int t = threadIdx.x;
  const int jl = t & 63;
  const int cg = __builtin_amdgcn_readfirstlane(t >> 6);  // 0..3, wave-uniform
  const int j0 = blockIdx.x * 64;
  const int j = j0 + jl;

  float acc[54];
  #pragma unroll
  for (int o = 0; o < 54; ++o) acc[o] = 0.f;

  const __hip_bfloat16* hp0 = h0 + (long)(cg * 256) * NPOS + j;
  const __hip_bfloat16* hp1 = h1 + (long)(cg * 256) * NPOS + j;
  const float* wp = Wh + cg * 256 * 54;
  const float* ivp = inv1 + cg * 256;
  const float* adp = add1 + cg * 256;
  for (int i = 0; i < 256; ++i) {
    float hv = __bfloat162float(hp0[(long)i * NPOS]) + __bfloat162float(hp1[(long)i * NPOS]);
    hv = fmaxf(hv * ivp[i] + adp[i], 0.f);   // fused bias+BN1+ReLU
    const float* wr_ = wp + i * 54;
    #pragma unroll
    for (int o = 0; o < 54; ++o) acc[o] += hv * wr_[o];
  }
  #pragma unroll
  for (int o = 0; o < 54; ++o) red[(cg * 64 + jl) * 54 + o] = acc[o];
  __syncthreads();

  // scores: 64 j x 9 pairs -> relu -> softmax over pair
  for (int idx = t; idx < 576; idx += 256) {
    int jj = idx / 9, pr = idx % 9;
    float s0 = bsel[2 * pr], s1 = bsel[2 * pr + 1];
    #pragma unroll
    for (int c = 0; c < 4; ++c) {
      s0 += red[(c * 64 + jj) * 54 + 2 * pr];
      s1 += red[(c * 64 + jj) * 54 + 2 * pr + 1];
    }
    s0 = fmaxf(s0, 0.f); s1 = fmaxf(s1, 0.f);
    float mx = fmaxf(s0, s1);
    float e0 = expf(s0 - mx), e1 = expf(s1 - mx);
    float inv = 1.f / (e0 + e1);
    int jg = j0 + jj;
    int nn = jg / HWSP, p = jg % HWSP;
    long off = ((long)nn * 1764 + p * 9 + pr) * 2;
    out[off] = e0 * inv;
    out[off + 1] = e1 * inv;
  }

  // boxes: 64 j x 36 -> BN -> relu -> *419
  float* outb = out + (long)NB * 1764 * 2;
  for (int idx = t; idx < 2304; idx += 256) {
    int jj = idx / 36, o = idx % 36;
    float v = bbox[o];
    #pragma unroll
    for (int c = 0; c < 4; ++c) v += red[(c * 64 + jj) * 54 + 18 + o];
    float iv = gb[o] / sqrtf(vab[o] + 1e-5f);
    v = v * iv + (beb[o] - mub[o] * iv);
    v = fmaxf(v, 0.f) * 419.f;
    int jg = j0 + jj;
    int nn = jg / HWSP, p = jg % HWSP;
    outb[((long)nn * 1764 + p * 9 + (o >> 2)) * 4 + (o & 3)] = v;
  }
}

extern "C" void kernel_launch(void* const* d_in, const int* in_sizes, int n_in,
                              void* d_out, int out_size, void* d_ws, size_t ws_size,
                              hipStream_t stream) {
  const float* x    = (const float*)d_in[0];
  const float* w1   = (const float*)d_in[1];
  const float* b1   = (const float*)d_in[2];
  const float* g1   = (const float*)d_in[3];
  const float* be1  = (const float*)d_in[4];
  const float* mu1  = (const float*)d_in[5];
  const float* va1  = (const float*)d_in[6];
  const float* wsel = (const float*)d_in[7];
  const float* bsel = (const float*)d_in[8];
  const float* wbox = (const float*)d_in[9];
  const float* bbox = (const float*)d_in[10];
  const float* gb   = (const float*)d_in[11];
  const float* beb  = (const float*)d_in[12];
  const float* mub  = (const float*)d_in[13];
  const float* vab  = (const float*)d_in[14];

  char* ws = (char*)d_ws;
  __hip_bfloat16* Wp = (__hip_bfloat16*)(ws);                    // 576*1024*32*2   = 37748736
  __hip_bfloat16* Xp = (__hip_bfloat16*)(ws + 37748736);         // 32*256*2048*2   = 33554432
  __hip_bfloat16* hb0 = (__hip_bfloat16*)(ws + 71303168);        // 1024*6272*2     = 12845056
  __hip_bfloat16* hb1 = (__hip_bfloat16*)(ws + 84148224);        // 1024*6272*2     = 12845056
  float* inv1        = (float*)(ws + 96993280);                  // 4096
  float* add1        = (float*)(ws + 96997376);                  // 4096
  float* Wh          = (float*)(ws + 97001472);                  // 1024*54*4       = 221184

  hipLaunchKernelGGL(pack_w, dim3(8192), dim3(256), 0, stream,
                     w1, b1, g1, be1, mu1, va1, wsel, wbox, Wp, inv1, add1, Wh);
  hipLaunchKernelGGL(pack_x, dim3(32, 32), dim3(256), 0, stream, x, Xp);
  hipLaunchKernelGGL(conv_mfma, dim3(8, 49, 2), dim3(256), 0, stream,
                     (const short8*)Wp, Xp, hb0, hb1);
  hipLaunchKernelGGL(head_fused, dim3(98), dim3(256), 0, stream,
                     hb0, hb1, Wh, inv1, add1, bsel, bbox, gb, beb, mub, vab, (float*)d_out);
}

// Round 8
// 472.008 us; speedup vs baseline: 1.1324x; 1.1324x over previous
//
#include <hip/hip_runtime.h>
#include <hip/hip_bf16.h>
#include <math.h>

#define CIN   2048
#define CMID  1024
#define NB    32
#define HWSP  196
#define NPOS  6272      // 32*196
#define WELEM 2097152   // CMID*CIN
#define NSTEP 288       // K-steps per z-chunk (BK=32, total K=18432 split in 2)

typedef __attribute__((ext_vector_type(4))) float f32x4;
typedef __attribute__((ext_vector_type(8))) short short8;

typedef const __attribute__((address_space(1))) unsigned int* as1_u32p;
typedef __attribute__((address_space(3))) unsigned int* as3_u32p;

__device__ __forceinline__ void gload_lds16(const void* g, void* l) {
  __builtin_amdgcn_global_load_lds((as1_u32p)g, (as3_u32p)l, 16, 0, 0);
}

// ---------------- pack weights: w1 -> Wpack[9][1024][2048] bf16, BN fold, head-weight transpose
__global__ __launch_bounds__(256) void pack_w(
    const float* __restrict__ w1, const float* __restrict__ b1,
    const float* __restrict__ g1, const float* __restrict__ be1,
    const float* __restrict__ mu1, const float* __restrict__ va1,
    const float* __restrict__ wsel, const float* __restrict__ wbox,
    __hip_bfloat16* __restrict__ Wp, float* __restrict__ inv1,
    float* __restrict__ add1, float* __restrict__ Wh)
{
  const int gid = blockIdx.x * 256 + threadIdx.x;
  if (gid < WELEM) {
    const float* src = w1 + (long)gid * 9;
    float v[9];
    #pragma unroll
    for (int k = 0; k < 9; ++k) v[k] = src[k];
    #pragma unroll
    for (int k = 0; k < 9; ++k)
      Wp[(long)k * WELEM + gid] = __float2bfloat16(v[k]);
  }
  if (gid < CMID) {
    float iv = g1[gid] / sqrtf(va1[gid] + 1e-5f);
    inv1[gid] = iv;
    add1[gid] = b1[gid] * iv + be1[gid] - mu1[gid] * iv;
  }
  if (gid < CMID * 54) {
    int co = gid / 54, o = gid % 54;
    Wh[gid] = (o < 18) ? wsel[o * CMID + co] : wbox[(o - 18) * CMID + co];
  }
}

// ---------------- pack x: NCHW fp32 -> Xpad[32][16][16][2048] bf16 (zero border)
__global__ __launch_bounds__(256) void pack_x(
    const float* __restrict__ x, __hip_bfloat16* __restrict__ Xp)
{
  __shared__ __hip_bfloat16 lx[64 * HWSP];
  const int n = blockIdx.x;      // 0..31
  const int cc = blockIdx.y;     // 0..31
  const int ci0 = cc * 64;
  const float* src = x + ((long)n * CIN + ci0) * HWSP;
  for (int i = threadIdx.x; i < 64 * HWSP; i += 256)
    lx[i] = __float2bfloat16(src[i]);
  __syncthreads();
  const int ci = threadIdx.x & 63;
  const int pq = threadIdx.x >> 6;   // 0..3
  __hip_bfloat16* dst = Xp + (long)n * 256 * CIN + ci0 + ci;
  const __hip_bfloat16 z = __float2bfloat16(0.f);
  #pragma unroll
  for (int k = 0; k < 64; ++k) {
    int pos = k * 4 + pq;
    int y = pos >> 4, xx = pos & 15;
    __hip_bfloat16 v = z;
    if (y >= 1 && y <= 14 && xx >= 1 && xx <= 14)
      v = lx[ci * HWSP + (y - 1) * 14 + (xx - 1)];
    dst[(long)pos * CIN] = v;
  }
}

// ---------------- conv 3x3 as shifted GEMMs, split-K halves (288 BK32-steps each)
// 128x128 tile, 4 waves x (64x64), 16x16x32 bf16 MFMA. Ring-3 LDS (48KB), vmcnt(4).
// XCD-aware remap: bid%8 (the XCD round-robin slot) selects a NTILE-slice, so each
// XCD's L2 holds a ~3.8MB B-slice reused by all 8 mtile-blocks; A streams from L3.
__global__ __launch_bounds__(256, 3) void conv_mfma(
    const __hip_bfloat16* __restrict__ Wp,
    const __hip_bfloat16* __restrict__ Xp,
    __hip_bfloat16* __restrict__ hout0,
    __hip_bfloat16* __restrict__ hout1)
{
  __shared__ char smem[3 * 16384];   // ring of 3: A 8KB + B 8KB each

  const int t = threadIdx.x;
  // grid.x = 448: r = XCD slot, q>>3 = ntile column, q&7 = mtile
  const int bx = blockIdx.x;
  const int r  = bx & 7;
  const int q  = bx >> 3;          // 0..55
  const int kidx = q >> 3;         // 0..6
  int mtile = q & 7;
  int ntile;
  if (kidx < 6) {
    ntile = r + 8 * kidx;          // XCD r owns ntiles {r, r+8, ..., r+40}
  } else {
    if (r != (q & 7)) return;      // ntile 48: one block per XCD (balanced)
    ntile = 48;
  }
  const int z = blockIdx.y;        // 0..1
  const int lane = t & 63;
  const int wv = t >> 6;          // 0..3
  const int wr2 = wv >> 1;        // 0..1 -> M offset *64
  const int wc2 = wv & 1;         // 0..1 -> N offset *64

  // staging: thread t covers rows (t>>2)+64*pass, 16B chunk (t&3), XOR-preswizzled source
  const int srow = t >> 2;                                   // 0..63
  const int swb = ((t & 3) << 4) ^ ((srow & 6) << 3);        // byte offset in 64B row

  const long arowbase = (long)(mtile * 128 + srow) * CIN + (swb >> 1);

  long bbase[2];
  #pragma unroll
  for (int i = 0; i < 2; ++i) {
    int jj = ntile * 128 + srow + 64 * i;
    int n0 = jj / HWSP, p0 = jj % HWSP;
    int hh = p0 / 14, ww = p0 % 14;
    bbase[i] = (long)(n0 * 256 + hh * 16 + ww) * CIN + (swb >> 1);
  }

  // frag-read swizzle constant (row&6 == fr&6 for 16-aligned row bases)
  const int fr = lane & 15;
  const int kgsw = (((lane >> 4) << 4) ^ ((fr & 6) << 3));

  f32x4 acc[4][4] = {};

  const int g0 = z * NSTEP;

  #define STAGE(gv, bi) do {                                                    \
    int g_ = (gv);                                                              \
    int kt_ = g_ >> 6;                                                          \
    int ck_ = (g_ & 63) << 5;                                                   \
    int kh_ = (kt_ * 11) >> 5;                                                  \
    int kw_ = kt_ - kh_ * 3;                                                    \
    char* d_ = smem + (bi) * 16384;                                             \
    const __hip_bfloat16* ap_ = Wp + (long)kt_ * WELEM + arowbase + ck_;        \
    _Pragma("unroll")                                                           \
    for (int i_ = 0; i_ < 2; ++i_)                                              \
      gload_lds16(ap_ + (long)i_ * 64 * CIN, d_ + i_ * 4096 + t * 16);          \
    long boff_ = (long)(kh_ * 16 + kw_) * CIN + ck_;                            \
    _Pragma("unroll")                                                           \
    for (int i_ = 0; i_ < 2; ++i_)                                              \
      gload_lds16(Xp + bbase[i_] + boff_, d_ + 8192 + i_ * 4096 + t * 16);      \
  } while (0)

  #define COMPUTE(bi) do {                                                      \
    const char* cb_ = smem + (bi) * 16384;                                      \
    short8 a_[4], b_[4];                                                        \
    _Pragma("unroll")                                                           \
    for (int i = 0; i < 4; ++i)                                                 \
      a_[i] = *(const short8*)(cb_ + (wr2 * 64 + i * 16 + fr) * 64 + kgsw);     \
    _Pragma("unroll")                                                           \
    for (int i = 0; i < 4; ++i)                                                 \
      b_[i] = *(const short8*)(cb_ + 8192 + (wc2 * 64 + i * 16 + fr) * 64 + kgsw); \
    _Pragma("unroll")                                                           \
    for (int m = 0; m < 4; ++m)                                                 \
      _Pragma("unroll")                                                         \
      for (int n = 0; n < 4; ++n)                                               \
        acc[m][n] = __builtin_amdgcn_mfma_f32_16x16x32_bf16(a_[m], b_[n], acc[m][n], 0, 0, 0); \
  } while (0)

  #define WAITV4() asm volatile("s_waitcnt vmcnt(4)" ::: "memory")
  #define WAITV0() asm volatile("s_waitcnt vmcnt(0)" ::: "memory")
  #define BAR() do { asm volatile("" ::: "memory");                             \
                     __builtin_amdgcn_s_barrier();                              \
                     asm volatile("" ::: "memory"); } while (0)

  STAGE(g0 + 0, 0);
  STAGE(g0 + 1, 1);

  int bc = 0, bs = 2;
  for (int s = 0; s < NSTEP - 2; ++s) {
    WAITV4();                 // my 4 loads for step s landed; s+1 still flying
    BAR();                    // all waves: step-s stages landed, step-(s-1) reads done
    STAGE(g0 + s + 2, bs);    // overwrite buffer last read at step s-1 (safe)
    COMPUTE(bc);              // consume step s
    bc = (bc == 2) ? 0 : bc + 1;
    bs = (bs == 2) ? 0 : bs + 1;
  }
  WAITV4(); BAR(); COMPUTE(bc);
  bc = (bc == 2) ? 0 : bc + 1;
  WAITV0(); BAR(); COMPUTE(bc);

  // epilogue: bf16 raw conv partials (BN/ReLU fused in head)
  __hip_bfloat16* dsth = z ? hout1 : hout0;
  const int rg = (lane >> 4) * 4;
  #pragma unroll
  for (int m = 0; m < 4; ++m) {
    const int co0 = mtile * 128 + wr2 * 64 + m * 16 + rg;
    #pragma unroll
    for (int r_ = 0; r_ < 4; ++r_) {
      const int co = co0 + r_;
      #pragma unroll
      for (int n = 0; n < 4; ++n) {
        const int j = ntile * 128 + wc2 * 64 + n * 16 + fr;
        dsth[(long)co * NPOS + j] = __float2bfloat16(acc[m][n][r_]);
      }
    }
  }
  #undef STAGE
  #undef COMPUTE
  #undef WAITV4
  #undef WAITV0
  #undef BAR
}

// ---------------- fused 1x1 heads: sum partials + BN1/ReLU + heads + softmax/BN/reshape
__global__ __launch_bounds__(256) void head_fused(
    const __hip_bfloat16* __restrict__ h0, const __hip_bfloat16* __restrict__ h1,
    const float* __restrict__ Wh,
    const float* __restrict__ inv1, const float* __restrict__ add1,
    const float* __restrict__ bsel, const float* __restrict__ bbox,
    const float* __restrict__ gb, const float* __restrict__ beb,
    const float* __restrict__ mub, const float* __restrict__ vab,
    float* __restrict__ out)
{
  __shared__ float red[4 * 64 * 54];
  const int t = threadIdx.x;
  const int jl = t & 63;
  const int cg = __builtin_amdgcn_readfirstlane(t >> 6);  // 0..3, wave-uniform
  const int j0 = blockIdx.x * 64;
  const int j = j0 + jl;

  float acc[54];
  #pragma unroll
  for (int o = 0; o < 54; ++o) acc[o] = 0.f;

  const __hip_bfloat16* hp0 = h0 + (long)(cg * 256) * NPOS + j;
  const __hip_bfloat16* hp1 = h1 + (long)(cg * 256) * NPOS + j;
  const float* wp = Wh + cg * 256 * 54;
  const float* ivp = inv1 + cg * 256;
  const float* adp = add1 + cg * 256;
  for (int i = 0; i < 256; ++i) {
    float hv = __bfloat162float(hp0[(long)i * NPOS]) + __bfloat162float(hp1[(long)i * NPOS]);
    hv = fmaxf(hv * ivp[i] + adp[i], 0.f);   // fused bias+BN1+ReLU
    const float* wr_ = wp + i * 54;
    #pragma unroll
    for (int o = 0; o < 54; ++o) acc[o] += hv * wr_[o];
  }
  #pragma unroll
  for (int o = 0; o < 54; ++o) red[(cg * 64 + jl) * 54 + o] = acc[o];
  __syncthreads();

  // scores: 64 j x 9 pairs -> relu -> softmax over pair
  for (int idx = t; idx < 576; idx += 256) {
    int jj = idx / 9, pr = idx % 9;
    float s0 = bsel[2 * pr], s1 = bsel[2 * pr + 1];
    #pragma unroll
    for (int c = 0; c < 4; ++c) {
      s0 += red[(c * 64 + jj) * 54 + 2 * pr];
      s1 += red[(c * 64 + jj) * 54 + 2 * pr + 1];
    }
    s0 = fmaxf(s0, 0.f); s1 = fmaxf(s1, 0.f);
    float mx = fmaxf(s0, s1);
    float e0 = expf(s0 - mx), e1 = expf(s1 - mx);
    float inv = 1.f / (e0 + e1);
    int jg = j0 + jj;
    int nn = jg / HWSP, p = jg % HWSP;
    long off = ((long)nn * 1764 + p * 9 + pr) * 2;
    out[off] = e0 * inv;
    out[off + 1] = e1 * inv;
  }

  // boxes: 64 j x 36 -> BN -> relu -> *419
  float* outb = out + (long)NB * 1764 * 2;
  for (int idx = t; idx < 2304; idx += 256) {
    int jj = idx / 36, o = idx % 36;
    float v = bbox[o];
    #pragma unroll
    for (int c = 0; c < 4; ++c) v += red[(c * 64 + jj) * 54 + 18 + o];
    float iv = gb[o] / sqrtf(vab[o] + 1e-5f);
    v = v * iv + (beb[o] - mub[o] * iv);
    v = fmaxf(v, 0.f) * 419.f;
    int jg = j0 + jj;
    int nn = jg / HWSP, p = jg % HWSP;
    outb[((long)nn * 1764 + p * 9 + (o >> 2)) * 4 + (o & 3)] = v;
  }
}

extern "C" void kernel_launch(void* const* d_in, const int* in_sizes, int n_in,
                              void* d_out, int out_size, void* d_ws, size_t ws_size,
                              hipStream_t stream) {
  const float* x    = (const float*)d_in[0];
  const float* w1   = (const float*)d_in[1];
  const float* b1   = (const float*)d_in[2];
  const float* g1   = (const float*)d_in[3];
  const float* be1  = (const float*)d_in[4];
  const float* mu1  = (const float*)d_in[5];
  const float* va1  = (const float*)d_in[6];
  const float* wsel = (const float*)d_in[7];
  const float* bsel = (const float*)d_in[8];
  const float* wbox = (const float*)d_in[9];
  const float* bbox = (const float*)d_in[10];
  const float* gb   = (const float*)d_in[11];
  const float* beb  = (const float*)d_in[12];
  const float* mub  = (const float*)d_in[13];
  const float* vab  = (const float*)d_in[14];

  char* ws = (char*)d_ws;
  __hip_bfloat16* Wp = (__hip_bfloat16*)(ws);                    // 9*1024*2048*2   = 37748736
  __hip_bfloat16* Xp = (__hip_bfloat16*)(ws + 37748736);         // 32*256*2048*2   = 33554432
  __hip_bfloat16* hb0 = (__hip_bfloat16*)(ws + 71303168);        // 1024*6272*2     = 12845056
  __hip_bfloat16* hb1 = (__hip_bfloat16*)(ws + 84148224);        // 1024*6272*2     = 12845056
  float* inv1        = (float*)(ws + 96993280);                  // 4096
  float* add1        = (float*)(ws + 96997376);                  // 4096
  float* Wh          = (float*)(ws + 97001472);                  // 1024*54*4       = 221184

  hipLaunchKernelGGL(pack_w, dim3(8192), dim3(256), 0, stream,
                     w1, b1, g1, be1, mu1, va1, wsel, wbox, Wp, inv1, add1, Wh);
  hipLaunchKernelGGL(pack_x, dim3(32, 32), dim3(256), 0, stream, x, Xp);
  hipLaunchKernelGGL(conv_mfma, dim3(448, 2), dim3(256), 0, stream,
                     Wp, Xp, hb0, hb1);
  hipLaunchKernelGGL(head_fused, dim3(98), dim3(256), 0, stream,
                     hb0, hb1, Wh, inv1, add1, bsel, bbox, gb, beb, mub, vab, (float*)d_out);
}